// Round 8
// baseline (798.709 us; speedup 1.0000x reference)
//
#include <hip/hip_runtime.h>

#define NN 4096
#define NE 65536
#define C 256
#define NL 3
#define NH 8
#define DH 32
#define EPS 1e-5f
#define SPLIT 4              // key-dim split for attention occupancy
#define KT8 (NN/128/SPLIT)   // 128-key tiles per split = 8
#define SR 512               // QK buffer row stride (Q cols 0..255, K cols 256..511)

typedef __bf16 bf16x8 __attribute__((ext_vector_type(8)));
typedef __bf16 bf16x4v __attribute__((ext_vector_type(4)));
typedef float f32x4 __attribute__((ext_vector_type(4)));
typedef short bf16x4s __attribute__((ext_vector_type(4)));   // 4 bf16 as i16x4

// scale * log2(e), folded into Q at projection time so softmax uses exp2
#define QSCALE (0.17677669529663687f * 1.4426950408889634f)

#define CC1 (C*C)            // 65536
#define CCL (NL*C*C)

// ---------------- weight prep: fp32 -> bf16; qkv stacked per layer ----------------
// Wb layout (units of CC1): gw1 @0 (3), gw2 @3 (3), qkv @6 (9: layer l at 6+3l,
// order q,k,v), wo @15 (3), mw1 @18 (6), mw2 @24 (6). Total 30 CC1.
__global__ __launch_bounds__(256) void prep_w(const float* __restrict__ s0,
        const float* __restrict__ s1, const float* __restrict__ s2,
        const float* __restrict__ s3, const float* __restrict__ s4,
        const float* __restrict__ s5, const float* __restrict__ s6,
        const float* __restrict__ s7, __bf16* __restrict__ dst) {
    int g = blockIdx.y;
    int i = (blockIdx.x*256 + threadIdx.x)*4;
    const float* src; int n;
    switch (g) {
        case 0: src=s0; n=3*CC1; break;
        case 1: src=s1; n=3*CC1; break;
        case 2: src=s2; n=3*CC1; break;
        case 3: src=s3; n=3*CC1; break;
        case 4: src=s4; n=3*CC1; break;
        case 5: src=s5; n=3*CC1; break;
        case 6: src=s6; n=6*CC1; break;
        default: src=s7; n=6*CC1; break;
    }
    if (i >= n) return;
    size_t off;
    if (g >= 2 && g <= 4) {                 // qkv: stack per layer
        int l = i >> 16, rem = i & (CC1-1);
        off = (size_t)(6 + 3*l + (g-2))*CC1 + rem;
    } else {
        size_t base = (g==0) ? 0 : (g==1) ? 3*(size_t)CC1 : (g==5) ? 15*(size_t)CC1
                    : (g==6) ? 18*(size_t)CC1 : 24*(size_t)CC1;
        off = base + i;
    }
    float4 t = *(const float4*)(src + i);
    bf16x4v o = {(__bf16)t.x, (__bf16)t.y, (__bf16)t.z, (__bf16)t.w};
    *(bf16x4v*)(dst + off) = o;
}

// ---------------- lin1 ----------------
__global__ __launch_bounds__(256) void lin1_kernel(const float* __restrict__ x,
        const float* __restrict__ w, const float* __restrict__ b,
        __bf16* __restrict__ out) {
    int n = blockIdx.x, c = threadIdx.x;
    out[(size_t)n*C + c] = (__bf16)(x[n]*w[c] + b[c]);
}

// ---------------- CSR build ----------------
__global__ __launch_bounds__(256) void hist_kernel(const int* __restrict__ ei,
        int* __restrict__ cnt) {
    int e = blockIdx.x*256 + threadIdx.x;
    atomicAdd(&cnt[ei[NE + e]], 1);
}

__global__ __launch_bounds__(256) void scan_kernel(const int* __restrict__ cnt,
        int* __restrict__ rowptr, int* __restrict__ cursor) {
    __shared__ int tot[256];
    __shared__ int pre[257];
    int t = threadIdx.x;
    int base = t*16;
    int local[16];
    int s = 0;
    #pragma unroll
    for (int i = 0; i < 16; i++) { local[i] = s; s += cnt[base+i]; }
    tot[t] = s;
    __syncthreads();
    if (t == 0) {
        int acc = 0;
        for (int i = 0; i < 256; i++) { pre[i] = acc; acc += tot[i]; }
        pre[256] = acc;
    }
    __syncthreads();
    int off = pre[t];
    #pragma unroll
    for (int i = 0; i < 16; i++) {
        rowptr[base+i] = off + local[i];
        cursor[base+i] = off + local[i];
    }
    if (t == 0) rowptr[NN] = pre[256];
}

__global__ __launch_bounds__(256) void fill_kernel(const int* __restrict__ ei,
        int* __restrict__ cursor, int* __restrict__ eidsrc) {
    int e = blockIdx.x*256 + threadIdx.x;
    int dst = ei[NE + e], src = ei[e];
    int pos = atomicAdd(&cursor[dst], 1);
    eidsrc[pos] = src;
}

// ---------------- GEMM body (whole-256-K staged per barrier pair) ----------------
// mode 0: out[row*Nout+col] = relu?((A+A2)@W^T + b0) + add1 + add2, optional stats
// mode 1 (qkv): Nout=768; col<256 -> QK[row*SR+col]*QSCALE (bias b0);
//               col<512 -> QK[row*SR+col] (bias b1); else V^T[(col-512)*NN+row] (b2)
#define AS2 258   // LDS row stride in bf16 (129 dwords, odd -> spread banks)
__device__ __forceinline__ void gemm_body(int bm, int bn, const __bf16* A,
        const float* A2f, const __bf16* A2b, const __bf16* W,
        const float* b0, const float* b1, const float* b2,
        const __bf16* add1, const __bf16* add2, __bf16* out, __bf16* vt,
        float* stats, int K, int Nout, int relu, int mode,
        __bf16* As, __bf16* Ws) {
    int tid = threadIdx.x;
    int wave = tid >> 6, lane = tid & 63;
    int ln = lane & 15, quad = lane >> 4;
    int r = tid >> 2, sg = tid & 3;
    f32x4 acc[4] = {};
    for (int k0 = 0; k0 < K; k0 += 256) {
        __syncthreads();
        #pragma unroll
        for (int i = 0; i < 4; i++) {
            int c = sg*16 + i*64;
            const __bf16* ap = &A[(size_t)(bm+r)*K + k0 + c];
            bf16x8 a0 = *(const bf16x8*)ap;
            bf16x8 a1 = *(const bf16x8*)(ap + 8);
            if (A2f) {
                const float* p = &A2f[(size_t)(bm+r)*K + k0 + c];
                float4 t0 = *(const float4*)p;
                float4 t1 = *(const float4*)(p+4);
                float4 t2 = *(const float4*)(p+8);
                float4 t3 = *(const float4*)(p+12);
                a0[0]=(__bf16)((float)a0[0]+t0.x); a0[1]=(__bf16)((float)a0[1]+t0.y);
                a0[2]=(__bf16)((float)a0[2]+t0.z); a0[3]=(__bf16)((float)a0[3]+t0.w);
                a0[4]=(__bf16)((float)a0[4]+t1.x); a0[5]=(__bf16)((float)a0[5]+t1.y);
                a0[6]=(__bf16)((float)a0[6]+t1.z); a0[7]=(__bf16)((float)a0[7]+t1.w);
                a1[0]=(__bf16)((float)a1[0]+t2.x); a1[1]=(__bf16)((float)a1[1]+t2.y);
                a1[2]=(__bf16)((float)a1[2]+t2.z); a1[3]=(__bf16)((float)a1[3]+t2.w);
                a1[4]=(__bf16)((float)a1[4]+t3.x); a1[5]=(__bf16)((float)a1[5]+t3.y);
                a1[6]=(__bf16)((float)a1[6]+t3.z); a1[7]=(__bf16)((float)a1[7]+t3.w);
            } else if (A2b) {
                const __bf16* p = &A2b[(size_t)(bm+r)*K + k0 + c];
                bf16x8 c0 = *(const bf16x8*)p;
                bf16x8 c1 = *(const bf16x8*)(p + 8);
                #pragma unroll
                for (int j = 0; j < 8; j++) {
                    a0[j] = (__bf16)((float)a0[j] + (float)c0[j]);
                    a1[j] = (__bf16)((float)a1[j] + (float)c1[j]);
                }
            }
            *(bf16x8*)&As[r*AS2 + c]     = a0;
            *(bf16x8*)&As[r*AS2 + c + 8] = a1;
            const __bf16* wp = &W[(size_t)(bn+r)*K + k0 + c];
            *(bf16x8*)&Ws[r*AS2 + c]     = *(const bf16x8*)wp;
            *(bf16x8*)&Ws[r*AS2 + c + 8] = *(const bf16x8*)(wp + 8);
        }
        __syncthreads();
        #pragma unroll
        for (int kt = 0; kt < 8; kt++) {
            bf16x8 bfr = *(const bf16x8*)&Ws[(wave*16+ln)*AS2 + kt*32 + quad*8];
            #pragma unroll
            for (int i = 0; i < 4; i++) {
                bf16x8 afr = *(const bf16x8*)&As[(i*16+ln)*AS2 + kt*32 + quad*8];
                acc[i] = __builtin_amdgcn_mfma_f32_16x16x32_bf16(afr, bfr, acc[i], 0, 0, 0);
            }
        }
    }
    int col = bn + wave*16 + ln;
    if (mode == 1) {
        float bsv = col < 256 ? b0[col] : (col < 512 ? b1[col-256] : b2[col-512]);
        if (col < 512) {
            float osc = col < 256 ? (float)QSCALE : 1.0f;
            #pragma unroll
            for (int i = 0; i < 4; i++)
                #pragma unroll
                for (int rr = 0; rr < 4; rr++)
                    out[(size_t)(bm + i*16 + quad*4 + rr)*SR + col] =
                        (__bf16)((acc[i][rr] + bsv) * osc);
        } else {
            int vrow = col - 512;
            #pragma unroll
            for (int i = 0; i < 4; i++) {
                bf16x4v pk = {(__bf16)(acc[i][0]+bsv), (__bf16)(acc[i][1]+bsv),
                              (__bf16)(acc[i][2]+bsv), (__bf16)(acc[i][3]+bsv)};
                *(bf16x4v*)&vt[(size_t)vrow*NN + bm + i*16 + quad*4] = pk;
            }
        }
        return;
    }
    float bsv = b0[col];
    float ssum = 0.f, ssq = 0.f;
    #pragma unroll
    for (int i = 0; i < 4; i++) {
        #pragma unroll
        for (int rr = 0; rr < 4; rr++) {
            int rw = bm + i*16 + quad*4 + rr;
            float vv = acc[i][rr] + bsv;
            if (relu) vv = fmaxf(vv, 0.f);
            size_t idx = (size_t)rw*Nout + col;
            if (add1) vv += (float)add1[idx];
            if (add2) vv += (float)add2[idx];
            out[idx] = (__bf16)vv;
            ssum += vv; ssq += vv*vv;
        }
    }
    if (stats) {
        ssum += __shfl_xor(ssum, 16); ssum += __shfl_xor(ssum, 32);
        ssq  += __shfl_xor(ssq, 16);  ssq  += __shfl_xor(ssq, 32);
        if (quad == 0) {
            atomicAdd(&stats[col], ssum);
            atomicAdd(&stats[Nout + col], ssq);
        }
    }
}

__global__ __launch_bounds__(256) void gemm_bf16(const __bf16* A,
        const float* A2f, const __bf16* A2b, const __bf16* W,
        const float* b0, const __bf16* add1, const __bf16* add2,
        __bf16* out, float* stats, int K, int Nout, int relu) {
    __shared__ __bf16 As[64*AS2];
    __shared__ __bf16 Ws[64*AS2];
    gemm_body(blockIdx.y*64, blockIdx.x*64, A, A2f, A2b, W, b0, nullptr, nullptr,
              add1, add2, out, nullptr, stats, K, Nout, relu, 0, As, Ws);
}

// ---------------- fused: stacked-QKV gemm (blocks 0..767) + CSR gather agg ----------------
__global__ __launch_bounds__(256) void qkv_agg_kernel(const __bf16* __restrict__ Hb,
        const __bf16* __restrict__ Wqkv, const float* __restrict__ bq,
        const float* __restrict__ bk, const float* __restrict__ bv,
        __bf16* __restrict__ qkout, __bf16* __restrict__ vtout,
        const int* __restrict__ rowptr, const int* __restrict__ eidsrc,
        float* __restrict__ agg) {
    __shared__ __bf16 As[64*AS2];
    __shared__ __bf16 Ws[64*AS2];
    int bx = blockIdx.x;
    if (bx < 768) {
        gemm_body((bx & 63)*64, (bx >> 6)*64, Hb, nullptr, nullptr, Wqkv,
                  bq, bk, bv, nullptr, nullptr, qkout, vtout, nullptr,
                  C, 768, 0, 1, As, Ws);
        return;
    }
    // agg: one node per wave, 4 channels per lane
    int tid = threadIdx.x;
    int wave = tid >> 6, lane = tid & 63;
    int node = (bx - 768)*4 + wave;
    int beg = rowptr[node], end = rowptr[node+1];
    float s0 = 0.f, s1 = 0.f, s2 = 0.f, s3 = 0.f;
    for (int e = beg; e < end; e++) {
        int src = eidsrc[e];
        bf16x4v hv = *(const bf16x4v*)&Hb[(size_t)src*C + lane*4];
        s0 += (float)hv[0]; s1 += (float)hv[1];
        s2 += (float)hv[2]; s3 += (float)hv[3];
    }
    float4 o = {s0, s1, s2, s3};
    *(float4*)&agg[(size_t)node*C + lane*4] = o;
}

// ---------------- BatchNorm apply ----------------
__global__ __launch_bounds__(256) void bn_apply_kernel(const __bf16* __restrict__ z,
        const float* __restrict__ stats, const float* __restrict__ g,
        const float* __restrict__ b, __bf16* __restrict__ outb,
        float* __restrict__ outf) {
    int idx4 = (blockIdx.x*256 + threadIdx.x) * 4;
    int c = idx4 & (C-1);
    bf16x4v zv = *(const bf16x4v*)&z[idx4];
    float4 st = *(const float4*)&stats[c];
    float4 sq = *(const float4*)&stats[C + c];
    float4 gv = *(const float4*)&g[c];
    float4 bv = *(const float4*)&b[c];
    float o[4];
    float m0 = st.x*(1.f/NN), m1 = st.y*(1.f/NN), m2 = st.z*(1.f/NN), m3 = st.w*(1.f/NN);
    o[0] = ((float)zv[0] - m0) * rsqrtf(sq.x*(1.f/NN) - m0*m0 + EPS) * gv.x + bv.x;
    o[1] = ((float)zv[1] - m1) * rsqrtf(sq.y*(1.f/NN) - m1*m1 + EPS) * gv.y + bv.y;
    o[2] = ((float)zv[2] - m2) * rsqrtf(sq.z*(1.f/NN) - m2*m2 + EPS) * gv.z + bv.z;
    o[3] = ((float)zv[3] - m3) * rsqrtf(sq.w*(1.f/NN) - m3*m3 + EPS) * gv.w + bv.w;
    if (outb) {
        bf16x4v ov = {(__bf16)o[0], (__bf16)o[1], (__bf16)o[2], (__bf16)o[3]};
        *(bf16x4v*)&outb[idx4] = ov;
    } else {
        float4 ov = {o[0], o[1], o[2], o[3]};
        *(float4*)&outf[idx4] = ov;
    }
}

// ---------------- flash attention: no LDS, no barriers ----------------
// grid (NN/128, NH, SPLIT). S^T = K·Q^T (A=K rows from global, B=Q regs);
// O^T = V^T·P^T (A=V^T b64 from global, B=P^T in regs from S^T). alpha and
// 1/l are per-lane (query=ln) in the O^T domain — no broadcast shuffles.
__global__ __launch_bounds__(256) void attn_kernel(const __bf16* __restrict__ qk,
        const __bf16* __restrict__ vt, __bf16* __restrict__ opart,
        float2* __restrict__ ml) {
    int tid = threadIdx.x;
    int wave = tid >> 6, lane = tid & 63;
    int ln = lane & 15, quad = lane >> 4;
    int head = blockIdx.y, hb = head * DH;
    int qb = blockIdx.x * 128;
    int z = blockIdx.z;

    bf16x8 qf[2];
    #pragma unroll
    for (int g = 0; g < 2; g++)
        qf[g] = *(const bf16x8*)&qk[(size_t)(qb + wave*32 + g*16 + ln)*SR + hb + quad*8];

    f32x4 ot[2][2] = {};     // [g][h]: D[m=dh quad*4+r][n=query ln]
    float m_[2] = {-1e30f, -1e30f}, l_[2] = {0.f, 0.f};

    for (int kt = z*KT8; kt < (z+1)*KT8; kt++) {
        int kb = kt * 128;
        // V^T fragments (A-operand of PV), issued early
        bf16x4s vf[8][2];
        #pragma unroll
        for (int sub = 0; sub < 8; sub++)
            #pragma unroll
            for (int h = 0; h < 2; h++)
                vf[sub][h] = *(const bf16x4s*)&vt[(size_t)(hb + h*16 + ln)*NN
                                                  + kb + sub*16 + quad*4];
        // QK^T: S^T[key][query], 8 subtiles x 2 query groups
        f32x4 st[2][8];
        #pragma unroll
        for (int sub = 0; sub < 8; sub++) {
            bf16x8 kf = *(const bf16x8*)&qk[(size_t)(kb + sub*16 + ln)*SR + 256 + hb + quad*8];
            f32x4 zz = {0.f,0.f,0.f,0.f};
            st[0][sub] = __builtin_amdgcn_mfma_f32_16x16x32_bf16(kf, qf[0], zz, 0, 0, 0);
            st[1][sub] = __builtin_amdgcn_mfma_f32_16x16x32_bf16(kf, qf[1], zz, 0, 0, 0);
        }
        #pragma unroll
        for (int g = 0; g < 2; g++) {
            float tm = st[g][0][0];
            #pragma unroll
            for (int sub = 0; sub < 8; sub++)
                #pragma unroll
                for (int rr = 0; rr < 4; rr++)
                    tm = fmaxf(tm, st[g][sub][rr]);
            tm = fmaxf(tm, __shfl_xor(tm, 16));
            tm = fmaxf(tm, __shfl_xor(tm, 32));
            float nm = fmaxf(m_[g], tm);
            float al = __builtin_amdgcn_exp2f(m_[g] - nm);
            m_[g] = nm;
            float ps = 0.f;
            union { __bf16 b[4]; bf16x4s s; } pf[8];
            #pragma unroll
            for (int sub = 0; sub < 8; sub++)
                #pragma unroll
                for (int rr = 0; rr < 4; rr++) {
                    float p = __builtin_amdgcn_exp2f(st[g][sub][rr] - nm);
                    pf[sub].b[rr] = (__bf16)p;
                    ps += p;
                }
            ps += __shfl_xor(ps, 16);
            ps += __shfl_xor(ps, 32);
            l_[g] = l_[g]*al + ps;
            #pragma unroll
            for (int rr = 0; rr < 4; rr++) {
                ot[g][0][rr] *= al;
                ot[g][1][rr] *= al;
            }
            #pragma unroll
            for (int sub = 0; sub < 8; sub++) {
                ot[g][0] = __builtin_amdgcn_mfma_f32_16x16x16bf16_1k(
                        vf[sub][0], pf[sub].s, ot[g][0], 0, 0, 0);
                ot[g][1] = __builtin_amdgcn_mfma_f32_16x16x16bf16_1k(
                        vf[sub][1], pf[sub].s, ot[g][1], 0, 0, 0);
            }
        }
    }
    #pragma unroll
    for (int g = 0; g < 2; g++) {
        float inv = 1.0f / l_[g];
        int qrow = qb + wave*32 + g*16 + ln;
        #pragma unroll
        for (int h = 0; h < 2; h++) {
            bf16x4v pk = {(__bf16)(ot[g][h][0]*inv), (__bf16)(ot[g][h][1]*inv),
                          (__bf16)(ot[g][h][2]*inv), (__bf16)(ot[g][h][3]*inv)};
            *(bf16x4v*)&opart[((size_t)z*NN + qrow)*C + hb + h*16 + quad*4] = pk;
        }
        if (quad == 0)
            ml[((size_t)z*NH + head)*NN + qrow] = make_float2(m_[g], l_[g]);
    }
}

// ---------------- combine split-K attention partials ----------------
__global__ __launch_bounds__(256) void attn_combine(const __bf16* __restrict__ opart,
        const float2* __restrict__ ml, __bf16* __restrict__ o) {
    int row = blockIdx.x, c = threadIdx.x;
    int head = c >> 5;
    float2 t[SPLIT];
    float M = -1e30f;
    #pragma unroll
    for (int z = 0; z < SPLIT; z++) {
        t[z] = ml[((size_t)z*NH + head)*NN + row];
        M = fmaxf(M, t[z].x);
    }
    float acc = 0.f, wsum = 0.f;
    #pragma unroll
    for (int z = 0; z < SPLIT; z++) {
        float w = t[z].y * __builtin_amdgcn_exp2f(t[z].x - M);
        acc += w * (float)opart[((size_t)z*NN + row)*C + c];
        wsum += w;
    }
    o[(size_t)row*C + c] = (__bf16)(acc / wsum);
}

extern "C" void kernel_launch(void* const* d_in, const int* in_sizes, int n_in,
                              void* d_out, int out_size, void* d_ws, size_t ws_size,
                              hipStream_t stream) {
    const float* x      = (const float*)d_in[0];
    const int*   ei     = (const int*)d_in[1];
    const float* lin1_w = (const float*)d_in[2];
    const float* lin1_b = (const float*)d_in[3];
    const float* gin_w1 = (const float*)d_in[4];
    const float* gin_b1 = (const float*)d_in[5];
    const float* gin_w2 = (const float*)d_in[6];
    const float* gin_b2 = (const float*)d_in[7];
    const float* wq = (const float*)d_in[8];
    const float* wk = (const float*)d_in[9];
    const float* wv = (const float*)d_in[10];
    const float* wo = (const float*)d_in[11];
    const float* bq = (const float*)d_in[12];
    const float* bk = (const float*)d_in[13];
    const float* bv = (const float*)d_in[14];
    const float* bo = (const float*)d_in[15];
    const float* bn1_g = (const float*)d_in[16];
    const float* bn1_b = (const float*)d_in[17];
    const float* bn2_g = (const float*)d_in[18];
    const float* bn2_b = (const float*)d_in[19];
    const float* bn3_g = (const float*)d_in[20];
    const float* bn3_b = (const float*)d_in[21];
    const float* mw1 = (const float*)d_in[22];
    const float* mb1 = (const float*)d_in[23];
    const float* mw2 = (const float*)d_in[24];
    const float* mb2 = (const float*)d_in[25];

    const size_t MB = 1u << 20;
    char* ws = (char*)d_ws;
    __bf16* Hb      = (__bf16*)(ws);            // 2 MB
    __bf16* h1b     = (__bf16*)(ws + 2*MB);     // 2 MB
    __bf16* h2b     = (__bf16*)(ws + 4*MB);     // 2 MB
    __bf16* zbuf    = (__bf16*)(ws + 6*MB);     // 2 MB (proj/ff2 pre-BN)
    __bf16* z1b     = (__bf16*)(ws + 8*MB);     // 2 MB
    __bf16* QKbuf   = (__bf16*)(ws + 10*MB);    // 4 MB  [N][SR]
    __bf16* Vt      = (__bf16*)(ws + 14*MB);    // 2 MB  [C][N]
    float*  agg     = (float*)(ws + 16*MB);     // 4 MB (dead after g1)
    float2* Oml     = (float2*)(ws + 16*MB);    // 1 MB (agg overlay, after g1)
    __bf16* Ob      = (__bf16*)(ws + 17*MB);    // 2 MB (agg overlay)
    __bf16* Opart   = (__bf16*)(ws + 20*MB);    // 8 MB
    __bf16* zbufG   = (__bf16*)(ws + 20*MB);    // 2 MB (pre-attn overlay)
    __bf16* hiddenb = (__bf16*)(ws + 20*MB);    // 4 MB (post-combine overlay)
    __bf16* Wb      = (__bf16*)(ws + 28*MB);    // 3.84 MB
    float*  stats   = (float*)(ws + 32*MB);     // 9 x 2C
    int*    cursor  = (int*)(ws + 32*MB + 64*1024);
    int*    rowptr  = (int*)(ws + 32*MB + 96*1024);
    int*    eidsrc  = (int*)(ws + 32*MB + 128*1024);

    dim3 blk(256);
    dim3 gemmCC(4, 64);

    prep_w<<<dim3(384, 8), blk, 0, stream>>>(gin_w1, gin_w2, wq, wk, wv, wo, mw1, mw2, Wb);
    hipMemsetAsync(stats, 0, 9 * 2 * C * sizeof(float), stream);
    lin1_kernel<<<NN, blk, 0, stream>>>(x, lin1_w, lin1_b, Hb);
    hipMemsetAsync(cursor, 0, NN * sizeof(int), stream);
    hist_kernel<<<NE/256, blk, 0, stream>>>(ei, cursor);
    scan_kernel<<<1, blk, 0, stream>>>(cursor, rowptr, cursor);
    fill_kernel<<<NE/256, blk, 0, stream>>>(ei, cursor, eidsrc);

    for (int l = 0; l < NL; l++) {
        const __bf16* gw1b = Wb + (size_t)l*CC1;
        const __bf16* gw2b = Wb + (size_t)(3+l)*CC1;
        const __bf16* wqkv = Wb + (size_t)(6+3*l)*CC1;
        const __bf16* wop  = Wb + (size_t)(15+l)*CC1;
        const __bf16* mw1p = Wb + (size_t)(18+2*l)*CC1;
        const __bf16* mw2p = Wb + (size_t)(24+2*l)*CC1;
        const float* gb1 = gin_b1 + (size_t)l*C;
        const float* gb2 = gin_b2 + (size_t)l*C;
        const float* lbq = bq + (size_t)l*C;
        const float* lbk = bk + (size_t)l*C;
        const float* lbv = bv + (size_t)l*C;
        const float* lbo = bo + (size_t)l*C;
        const float* lmb1 = mb1 + (size_t)l*2*C;
        const float* lmb2 = mb2 + (size_t)l*C;
        float* st1 = stats + (size_t)l*3*2*C;
        float* st2 = st1 + 2*C;
        float* st3 = st2 + 2*C;

        // ---- fused stacked-QKV projection + gather aggregation ----
        qkv_agg_kernel<<<768 + NN/4, blk, 0, stream>>>(Hb, wqkv, lbq, lbk, lbv,
                QKbuf, Vt, rowptr, eidsrc, agg);
        // ---- GIN MLP ----
        gemm_bf16<<<gemmCC, blk, 0, stream>>>(Hb, agg, nullptr, gw1b, gb1,
                nullptr, nullptr, z1b, nullptr, C, C, 1);
        gemm_bf16<<<gemmCC, blk, 0, stream>>>(z1b, nullptr, nullptr, gw2b, gb2,
                Hb, nullptr, zbufG, st1, C, C, 0);
        bn_apply_kernel<<<NN/4, blk, 0, stream>>>(zbufG, st1, bn1_g + (size_t)l*C,
                bn1_b + (size_t)l*C, h1b, nullptr);
        // ---- attention ----
        attn_kernel<<<dim3(NN/128, NH, SPLIT), blk, 0, stream>>>(QKbuf, Vt, Opart, Oml);
        attn_combine<<<NN, blk, 0, stream>>>(Opart, Oml, Ob);
        gemm_bf16<<<gemmCC, blk, 0, stream>>>(Ob, nullptr, nullptr, wop, lbo,
                Hb, nullptr, zbuf, st2, C, C, 0);
        bn_apply_kernel<<<NN/4, blk, 0, stream>>>(zbuf, st2, bn2_g + (size_t)l*C,
                bn2_b + (size_t)l*C, h2b, nullptr);
        // ---- feedforward ----
        gemm_bf16<<<dim3(8, 64), blk, 0, stream>>>(h1b, nullptr, h2b, mw1p, lmb1,
                nullptr, nullptr, hiddenb, nullptr, C, 2*C, 1);
        gemm_bf16<<<gemmCC, blk, 0, stream>>>(hiddenb, nullptr, nullptr, mw2p, lmb2,
                h1b, h2b, zbuf, st3, 2*C, C, 0);
        if (l == NL-1)
            bn_apply_kernel<<<NN/4, blk, 0, stream>>>(zbuf, st3, bn3_g + (size_t)l*C,
                    bn3_b + (size_t)l*C, nullptr, (float*)d_out);
        else
            bn_apply_kernel<<<NN/4, blk, 0, stream>>>(zbuf, st3, bn3_g + (size_t)l*C,
                    bn3_b + (size_t)l*C, Hb, nullptr);
    }
}

// Round 9
// 602.811 us; speedup vs baseline: 1.3250x; 1.3250x over previous
//
#include <hip/hip_runtime.h>

#define NN 4096
#define NE 65536
#define C 256
#define NL 3
#define NH 8
#define DH 32
#define EPS 1e-5f
#define SPLIT 4              // key-dim split for attention occupancy
#define KT8 (NN/128/SPLIT)   // 128-key tiles per split = 8
#define SR 512               // QK buffer row stride (Q cols 0..255, K cols 256..511)

typedef __bf16 bf16x8 __attribute__((ext_vector_type(8)));
typedef __bf16 bf16x4v __attribute__((ext_vector_type(4)));
typedef float f32x4 __attribute__((ext_vector_type(4)));
typedef short bf16x4s __attribute__((ext_vector_type(4)));   // 4 bf16 as i16x4

// scale * log2(e), folded into Q at projection time so softmax uses exp2
#define QSCALE (0.17677669529663687f * 1.4426950408889634f)

#define CC1 (C*C)            // 65536
#define CCL (NL*C*C)

// ---------------- weight prep: fp32 -> bf16; qkv stacked per layer ----------------
// Wb layout (units of CC1): gw1 @0 (3), gw2 @3 (3), qkv @6 (9: layer l at 6+3l,
// order q,k,v), wo @15 (3), mw1 @18 (6), mw2 @24 (6). Total 30 CC1.
__global__ __launch_bounds__(256) void prep_w(const float* __restrict__ s0,
        const float* __restrict__ s1, const float* __restrict__ s2,
        const float* __restrict__ s3, const float* __restrict__ s4,
        const float* __restrict__ s5, const float* __restrict__ s6,
        const float* __restrict__ s7, __bf16* __restrict__ dst) {
    int g = blockIdx.y;
    int i = (blockIdx.x*256 + threadIdx.x)*4;
    const float* src; int n;
    switch (g) {
        case 0: src=s0; n=3*CC1; break;
        case 1: src=s1; n=3*CC1; break;
        case 2: src=s2; n=3*CC1; break;
        case 3: src=s3; n=3*CC1; break;
        case 4: src=s4; n=3*CC1; break;
        case 5: src=s5; n=3*CC1; break;
        case 6: src=s6; n=6*CC1; break;
        default: src=s7; n=6*CC1; break;
    }
    if (i >= n) return;
    size_t off;
    if (g >= 2 && g <= 4) {                 // qkv: stack per layer
        int l = i >> 16, rem = i & (CC1-1);
        off = (size_t)(6 + 3*l + (g-2))*CC1 + rem;
    } else {
        size_t base = (g==0) ? 0 : (g==1) ? 3*(size_t)CC1 : (g==5) ? 15*(size_t)CC1
                    : (g==6) ? 18*(size_t)CC1 : 24*(size_t)CC1;
        off = base + i;
    }
    float4 t = *(const float4*)(src + i);
    bf16x4v o = {(__bf16)t.x, (__bf16)t.y, (__bf16)t.z, (__bf16)t.w};
    *(bf16x4v*)(dst + off) = o;
}

// ---------------- lin1 ----------------
__global__ __launch_bounds__(256) void lin1_kernel(const float* __restrict__ x,
        const float* __restrict__ w, const float* __restrict__ b,
        __bf16* __restrict__ out) {
    int n = blockIdx.x, c = threadIdx.x;
    out[(size_t)n*C + c] = (__bf16)(x[n]*w[c] + b[c]);
}

// ---------------- CSR build ----------------
__global__ __launch_bounds__(256) void hist_kernel(const int* __restrict__ ei,
        int* __restrict__ cnt) {
    int e = blockIdx.x*256 + threadIdx.x;
    atomicAdd(&cnt[ei[NE + e]], 1);
}

__global__ __launch_bounds__(256) void scan_kernel(const int* __restrict__ cnt,
        int* __restrict__ rowptr, int* __restrict__ cursor) {
    __shared__ int tot[256];
    __shared__ int pre[257];
    int t = threadIdx.x;
    int base = t*16;
    int local[16];
    int s = 0;
    #pragma unroll
    for (int i = 0; i < 16; i++) { local[i] = s; s += cnt[base+i]; }
    tot[t] = s;
    __syncthreads();
    if (t == 0) {
        int acc = 0;
        for (int i = 0; i < 256; i++) { pre[i] = acc; acc += tot[i]; }
        pre[256] = acc;
    }
    __syncthreads();
    int off = pre[t];
    #pragma unroll
    for (int i = 0; i < 16; i++) {
        rowptr[base+i] = off + local[i];
        cursor[base+i] = off + local[i];
    }
    if (t == 0) rowptr[NN] = pre[256];
}

__global__ __launch_bounds__(256) void fill_kernel(const int* __restrict__ ei,
        int* __restrict__ cursor, int* __restrict__ eidsrc) {
    int e = blockIdx.x*256 + threadIdx.x;
    int dst = ei[NE + e], src = ei[e];
    int pos = atomicAdd(&cursor[dst], 1);
    eidsrc[pos] = src;
}

// ---------------- GEMM body, BK=64 (18.4 KB LDS -> high occupancy) ----------------
// mode 0: out = relu?((A [+A2f|+A2b])@W^T + b0) + add1 + add2, optional stats
// mode 1 (qkv): Nout=768; col<256 -> QK[row*SR+col]*QSCALE (bias b0);
//               col<512 -> QK[row*SR+col] (bias b1); else V^T[(col-512)*NN+row] (b2)
#define GS 72   // LDS row stride in bf16 (144 B: 2-way bank alias, free)
__device__ __forceinline__ void gemm_body(int bm, int bn, const __bf16* A,
        const float* A2f, const __bf16* A2b, const __bf16* W,
        const float* b0, const float* b1, const float* b2,
        const __bf16* add1, const __bf16* add2, __bf16* out, __bf16* vt,
        float* stats, int K, int Nout, int relu, int mode,
        __bf16* As, __bf16* Ws) {
    int tid = threadIdx.x;
    int wave = tid >> 6, lane = tid & 63;
    int ln = lane & 15, quad = lane >> 4;
    int row = tid >> 2, kseg = (tid & 3) * 16;
    f32x4 acc[4] = {};
    for (int k0 = 0; k0 < K; k0 += 64) {
        __syncthreads();
        {
            const __bf16* ap = &A[(size_t)(bm+row)*K + k0 + kseg];
            bf16x8 a0 = *(const bf16x8*)ap;
            bf16x8 a1 = *(const bf16x8*)(ap + 8);
            if (A2f) {
                const float* p = &A2f[(size_t)(bm+row)*K + k0 + kseg];
                float4 t0 = *(const float4*)p;
                float4 t1 = *(const float4*)(p+4);
                float4 t2 = *(const float4*)(p+8);
                float4 t3 = *(const float4*)(p+12);
                a0[0]=(__bf16)((float)a0[0]+t0.x); a0[1]=(__bf16)((float)a0[1]+t0.y);
                a0[2]=(__bf16)((float)a0[2]+t0.z); a0[3]=(__bf16)((float)a0[3]+t0.w);
                a0[4]=(__bf16)((float)a0[4]+t1.x); a0[5]=(__bf16)((float)a0[5]+t1.y);
                a0[6]=(__bf16)((float)a0[6]+t1.z); a0[7]=(__bf16)((float)a0[7]+t1.w);
                a1[0]=(__bf16)((float)a1[0]+t2.x); a1[1]=(__bf16)((float)a1[1]+t2.y);
                a1[2]=(__bf16)((float)a1[2]+t2.z); a1[3]=(__bf16)((float)a1[3]+t2.w);
                a1[4]=(__bf16)((float)a1[4]+t3.x); a1[5]=(__bf16)((float)a1[5]+t3.y);
                a1[6]=(__bf16)((float)a1[6]+t3.z); a1[7]=(__bf16)((float)a1[7]+t3.w);
            } else if (A2b) {
                const __bf16* p = &A2b[(size_t)(bm+row)*K + k0 + kseg];
                bf16x8 c0 = *(const bf16x8*)p;
                bf16x8 c1 = *(const bf16x8*)(p + 8);
                #pragma unroll
                for (int j = 0; j < 8; j++) {
                    a0[j] = (__bf16)((float)a0[j] + (float)c0[j]);
                    a1[j] = (__bf16)((float)a1[j] + (float)c1[j]);
                }
            }
            *(bf16x8*)&As[row*GS + kseg]     = a0;
            *(bf16x8*)&As[row*GS + kseg + 8] = a1;
            const __bf16* wp = &W[(size_t)(bn+row)*K + k0 + kseg];
            *(bf16x8*)&Ws[row*GS + kseg]     = *(const bf16x8*)wp;
            *(bf16x8*)&Ws[row*GS + kseg + 8] = *(const bf16x8*)(wp + 8);
        }
        __syncthreads();
        #pragma unroll
        for (int kt2 = 0; kt2 < 2; kt2++) {
            bf16x8 bfr = *(const bf16x8*)&Ws[(wave*16+ln)*GS + kt2*32 + quad*8];
            #pragma unroll
            for (int i = 0; i < 4; i++) {
                bf16x8 afr = *(const bf16x8*)&As[(i*16+ln)*GS + kt2*32 + quad*8];
                acc[i] = __builtin_amdgcn_mfma_f32_16x16x32_bf16(afr, bfr, acc[i], 0, 0, 0);
            }
        }
    }
    int col = bn + wave*16 + ln;
    if (mode == 1) {
        float bsv = col < 256 ? b0[col] : (col < 512 ? b1[col-256] : b2[col-512]);
        if (col < 512) {
            float osc = col < 256 ? (float)QSCALE : 1.0f;
            #pragma unroll
            for (int i = 0; i < 4; i++)
                #pragma unroll
                for (int rr = 0; rr < 4; rr++)
                    out[(size_t)(bm + i*16 + quad*4 + rr)*SR + col] =
                        (__bf16)((acc[i][rr] + bsv) * osc);
        } else {
            int vrow = col - 512;
            #pragma unroll
            for (int i = 0; i < 4; i++) {
                bf16x4v pk = {(__bf16)(acc[i][0]+bsv), (__bf16)(acc[i][1]+bsv),
                              (__bf16)(acc[i][2]+bsv), (__bf16)(acc[i][3]+bsv)};
                *(bf16x4v*)&vt[(size_t)vrow*NN + bm + i*16 + quad*4] = pk;
            }
        }
        return;
    }
    float bsv = b0[col];
    float ssum = 0.f, ssq = 0.f;
    #pragma unroll
    for (int i = 0; i < 4; i++) {
        #pragma unroll
        for (int rr = 0; rr < 4; rr++) {
            int rw = bm + i*16 + quad*4 + rr;
            float vv = acc[i][rr] + bsv;
            if (relu) vv = fmaxf(vv, 0.f);
            size_t idx = (size_t)rw*Nout + col;
            if (add1) vv += (float)add1[idx];
            if (add2) vv += (float)add2[idx];
            out[idx] = (__bf16)vv;
            ssum += vv; ssq += vv*vv;
        }
    }
    if (stats) {
        ssum += __shfl_xor(ssum, 16); ssum += __shfl_xor(ssum, 32);
        ssq  += __shfl_xor(ssq, 16);  ssq  += __shfl_xor(ssq, 32);
        if (quad == 0) {
            atomicAdd(&stats[col], ssum);
            atomicAdd(&stats[Nout + col], ssq);
        }
    }
}

__global__ __launch_bounds__(256) void gemm_bf16(const __bf16* A,
        const float* A2f, const __bf16* A2b, const __bf16* W, const float* b0,
        const __bf16* add1, const __bf16* add2,
        __bf16* out, float* stats, int K, int Nout, int relu) {
    __shared__ __bf16 As[64*GS];
    __shared__ __bf16 Ws[64*GS];
    gemm_body(blockIdx.y*64, blockIdx.x*64, A, A2f, A2b, W, b0, nullptr, nullptr,
              add1, add2, out, nullptr, stats, K, Nout, relu, 0, As, Ws);
}

// ---------------- fused: stacked-QKV gemm (blocks 0..767) + CSR gather agg ----------------
__global__ __launch_bounds__(256) void qkv_agg_kernel(const __bf16* __restrict__ Hb,
        const __bf16* __restrict__ Wqkv, const float* __restrict__ bq,
        const float* __restrict__ bk, const float* __restrict__ bv,
        __bf16* __restrict__ qkout, __bf16* __restrict__ vtout,
        const int* __restrict__ rowptr, const int* __restrict__ eidsrc,
        float* __restrict__ agg) {
    __shared__ __bf16 As[64*GS];
    __shared__ __bf16 Ws[64*GS];
    int bx = blockIdx.x;
    if (bx < 768) {
        gemm_body((bx & 63)*64, (bx >> 6)*64, Hb, nullptr, nullptr, Wqkv,
                  bq, bk, bv, nullptr, nullptr, qkout, vtout, nullptr,
                  C, 768, 0, 1, As, Ws);
        return;
    }
    // agg: one node per wave, 4 channels per lane
    int tid = threadIdx.x;
    int wave = tid >> 6, lane = tid & 63;
    int node = (bx - 768)*4 + wave;
    int beg = rowptr[node], end = rowptr[node+1];
    float s0 = 0.f, s1 = 0.f, s2 = 0.f, s3 = 0.f;
    for (int e = beg; e < end; e++) {
        int src = eidsrc[e];
        bf16x4v hv = *(const bf16x4v*)&Hb[(size_t)src*C + lane*4];
        s0 += (float)hv[0]; s1 += (float)hv[1];
        s2 += (float)hv[2]; s3 += (float)hv[3];
    }
    float4 o = {s0, s1, s2, s3};
    *(float4*)&agg[(size_t)node*C + lane*4] = o;
}

// ---------------- BatchNorm apply ----------------
__global__ __launch_bounds__(256) void bn_apply_kernel(const __bf16* __restrict__ z,
        const float* __restrict__ stats, const float* __restrict__ g,
        const float* __restrict__ b, __bf16* __restrict__ outb,
        float* __restrict__ outf) {
    int idx4 = (blockIdx.x*256 + threadIdx.x) * 4;
    int c = idx4 & (C-1);
    bf16x4v zv = *(const bf16x4v*)&z[idx4];
    float4 st = *(const float4*)&stats[c];
    float4 sq = *(const float4*)&stats[C + c];
    float4 gv = *(const float4*)&g[c];
    float4 bv = *(const float4*)&b[c];
    float o[4];
    float m0 = st.x*(1.f/NN), m1 = st.y*(1.f/NN), m2 = st.z*(1.f/NN), m3 = st.w*(1.f/NN);
    o[0] = ((float)zv[0] - m0) * rsqrtf(sq.x*(1.f/NN) - m0*m0 + EPS) * gv.x + bv.x;
    o[1] = ((float)zv[1] - m1) * rsqrtf(sq.y*(1.f/NN) - m1*m1 + EPS) * gv.y + bv.y;
    o[2] = ((float)zv[2] - m2) * rsqrtf(sq.z*(1.f/NN) - m2*m2 + EPS) * gv.z + bv.z;
    o[3] = ((float)zv[3] - m3) * rsqrtf(sq.w*(1.f/NN) - m3*m3 + EPS) * gv.w + bv.w;
    if (outb) {
        bf16x4v ov = {(__bf16)o[0], (__bf16)o[1], (__bf16)o[2], (__bf16)o[3]};
        *(bf16x4v*)&outb[idx4] = ov;
    } else {
        float4 ov = {o[0], o[1], o[2], o[3]};
        *(float4*)&outf[idx4] = ov;
    }
}

// ---------------- flash attention: K staged in LDS, V^T/P in registers ----------------
// grid (NN/128, NH, SPLIT). S^T = K·Q^T (A=K rows from LDS, B=Q regs);
// O^T = V^T·P^T (A=V^T b64 from global, prefetched before the barrier;
// B=P^T in regs). alpha and 1/l are per-lane (query=ln) — no broadcast shuffles.
__global__ __launch_bounds__(256) void attn_kernel(const __bf16* __restrict__ qk,
        const __bf16* __restrict__ vt, __bf16* __restrict__ opart,
        float2* __restrict__ ml) {
    __shared__ __bf16 Ks[128*36];           // [key][dh], 9216 B
    int tid = threadIdx.x;
    int wave = tid >> 6, lane = tid & 63;
    int ln = lane & 15, quad = lane >> 4;
    int head = blockIdx.y, hb = head * DH;
    int qb = blockIdx.x * 128;
    int z = blockIdx.z;

    bf16x8 qf[2];
    #pragma unroll
    for (int g = 0; g < 2; g++)
        qf[g] = *(const bf16x8*)&qk[(size_t)(qb + wave*32 + g*16 + ln)*SR + hb + quad*8];

    f32x4 ot[2][2] = {};     // [g][h]: D[m=dh quad*4+r][n=query ln]
    float m_[2] = {-1e30f, -1e30f}, l_[2] = {0.f, 0.f};

    int srow = tid >> 1, sseg = (tid & 1) * 16;   // K staging: 128 rows, 2 thr/row
    for (int kt = z*KT8; kt < (z+1)*KT8; kt++) {
        int kb = kt * 128;
        // V^T fragments (A-operand of PV) from global — issued before the
        // barrier so their latency drains under QK^T + softmax
        bf16x4s vf[8][2];
        #pragma unroll
        for (int sub = 0; sub < 8; sub++)
            #pragma unroll
            for (int h = 0; h < 2; h++)
                vf[sub][h] = *(const bf16x4s*)&vt[(size_t)(hb + h*16 + ln)*NN
                                                  + kb + sub*16 + quad*4];
        __syncthreads();
        {
            const __bf16* kp = &qk[(size_t)(kb+srow)*SR + 256 + hb + sseg];
            *(bf16x8*)&Ks[srow*36 + sseg]     = *(const bf16x8*)kp;
            *(bf16x8*)&Ks[srow*36 + sseg + 8] = *(const bf16x8*)(kp + 8);
        }
        __syncthreads();
        // QK^T: S^T[key][query], 8 subtiles x 2 query groups
        f32x4 st[2][8];
        #pragma unroll
        for (int sub = 0; sub < 8; sub++) {
            bf16x8 kf = *(const bf16x8*)&Ks[(sub*16+ln)*36 + quad*8];
            f32x4 zz = {0.f,0.f,0.f,0.f};
            st[0][sub] = __builtin_amdgcn_mfma_f32_16x16x32_bf16(kf, qf[0], zz, 0, 0, 0);
            st[1][sub] = __builtin_amdgcn_mfma_f32_16x16x32_bf16(kf, qf[1], zz, 0, 0, 0);
        }
        #pragma unroll
        for (int g = 0; g < 2; g++) {
            float tm = st[g][0][0];
            #pragma unroll
            for (int sub = 0; sub < 8; sub++)
                #pragma unroll
                for (int rr = 0; rr < 4; rr++)
                    tm = fmaxf(tm, st[g][sub][rr]);
            tm = fmaxf(tm, __shfl_xor(tm, 16));
            tm = fmaxf(tm, __shfl_xor(tm, 32));
            float nm = fmaxf(m_[g], tm);
            float al = __builtin_amdgcn_exp2f(m_[g] - nm);
            m_[g] = nm;
            float ps = 0.f;
            union { __bf16 b[4]; bf16x4s s; } pf[8];
            #pragma unroll
            for (int sub = 0; sub < 8; sub++)
                #pragma unroll
                for (int rr = 0; rr < 4; rr++) {
                    float p = __builtin_amdgcn_exp2f(st[g][sub][rr] - nm);
                    pf[sub].b[rr] = (__bf16)p;
                    ps += p;
                }
            ps += __shfl_xor(ps, 16);
            ps += __shfl_xor(ps, 32);
            l_[g] = l_[g]*al + ps;
            #pragma unroll
            for (int rr = 0; rr < 4; rr++) {
                ot[g][0][rr] *= al;
                ot[g][1][rr] *= al;
            }
            #pragma unroll
            for (int sub = 0; sub < 8; sub++) {
                ot[g][0] = __builtin_amdgcn_mfma_f32_16x16x16bf16_1k(
                        vf[sub][0], pf[sub].s, ot[g][0], 0, 0, 0);
                ot[g][1] = __builtin_amdgcn_mfma_f32_16x16x16bf16_1k(
                        vf[sub][1], pf[sub].s, ot[g][1], 0, 0, 0);
            }
        }
    }
    #pragma unroll
    for (int g = 0; g < 2; g++) {
        float inv = 1.0f / l_[g];
        int qrow = qb + wave*32 + g*16 + ln;
        #pragma unroll
        for (int h = 0; h < 2; h++) {
            bf16x4v pk = {(__bf16)(ot[g][h][0]*inv), (__bf16)(ot[g][h][1]*inv),
                          (__bf16)(ot[g][h][2]*inv), (__bf16)(ot[g][h][3]*inv)};
            *(bf16x4v*)&opart[((size_t)z*NN + qrow)*C + hb + h*16 + quad*4] = pk;
        }
        if (quad == 0)
            ml[((size_t)z*NH + head)*NN + qrow] = make_float2(m_[g], l_[g]);
    }
}

// ---------------- combine split-K attention partials ----------------
__global__ __launch_bounds__(256) void attn_combine(const __bf16* __restrict__ opart,
        const float2* __restrict__ ml, __bf16* __restrict__ o) {
    int row = blockIdx.x, c = threadIdx.x;
    int head = c >> 5;
    float2 t[SPLIT];
    float M = -1e30f;
    #pragma unroll
    for (int z = 0; z < SPLIT; z++) {
        t[z] = ml[((size_t)z*NH + head)*NN + row];
        M = fmaxf(M, t[z].x);
    }
    float acc = 0.f, wsum = 0.f;
    #pragma unroll
    for (int z = 0; z < SPLIT; z++) {
        float w = t[z].y * __builtin_amdgcn_exp2f(t[z].x - M);
        acc += w * (float)opart[((size_t)z*NN + row)*C + c];
        wsum += w;
    }
    o[(size_t)row*C + c] = (__bf16)(acc / wsum);
}

extern "C" void kernel_launch(void* const* d_in, const int* in_sizes, int n_in,
                              void* d_out, int out_size, void* d_ws, size_t ws_size,
                              hipStream_t stream) {
    const float* x      = (const float*)d_in[0];
    const int*   ei     = (const int*)d_in[1];
    const float* lin1_w = (const float*)d_in[2];
    const float* lin1_b = (const float*)d_in[3];
    const float* gin_w1 = (const float*)d_in[4];
    const float* gin_b1 = (const float*)d_in[5];
    const float* gin_w2 = (const float*)d_in[6];
    const float* gin_b2 = (const float*)d_in[7];
    const float* wq = (const float*)d_in[8];
    const float* wk = (const float*)d_in[9];
    const float* wv = (const float*)d_in[10];
    const float* wo = (const float*)d_in[11];
    const float* bq = (const float*)d_in[12];
    const float* bk = (const float*)d_in[13];
    const float* bv = (const float*)d_in[14];
    const float* bo = (const float*)d_in[15];
    const float* bn1_g = (const float*)d_in[16];
    const float* bn1_b = (const float*)d_in[17];
    const float* bn2_g = (const float*)d_in[18];
    const float* bn2_b = (const float*)d_in[19];
    const float* bn3_g = (const float*)d_in[20];
    const float* bn3_b = (const float*)d_in[21];
    const float* mw1 = (const float*)d_in[22];
    const float* mb1 = (const float*)d_in[23];
    const float* mw2 = (const float*)d_in[24];
    const float* mb2 = (const float*)d_in[25];

    const size_t MB = 1u << 20;
    char* ws = (char*)d_ws;
    __bf16* Hb      = (__bf16*)(ws);            // 2 MB
    __bf16* h1b     = (__bf16*)(ws + 2*MB);     // 2 MB
    __bf16* h2b     = (__bf16*)(ws + 4*MB);     // 2 MB
    __bf16* zbuf    = (__bf16*)(ws + 6*MB);     // 2 MB (proj/ff2 pre-BN)
    __bf16* z1b     = (__bf16*)(ws + 8*MB);     // 2 MB
    __bf16* QKbuf   = (__bf16*)(ws + 10*MB);    // 4 MB  [N][SR]
    __bf16* Vt      = (__bf16*)(ws + 14*MB);    // 2 MB  [C][N]
    float*  agg     = (float*)(ws + 16*MB);     // 4 MB (dead after g1)
    float2* Oml     = (float2*)(ws + 16*MB);    // 1 MB (agg overlay, after g1)
    __bf16* Ob      = (__bf16*)(ws + 17*MB);    // 2 MB (agg overlay)
    __bf16* Opart   = (__bf16*)(ws + 20*MB);    // 8 MB
    __bf16* zbufG   = (__bf16*)(ws + 20*MB);    // 2 MB (pre-attn overlay)
    __bf16* hiddenb = (__bf16*)(ws + 20*MB);    // 4 MB (post-combine overlay)
    __bf16* Wb      = (__bf16*)(ws + 28*MB);    // 3.84 MB
    float*  stats   = (float*)(ws + 32*MB);     // 9 x 2C
    int*    cursor  = (int*)(ws + 32*MB + 64*1024);
    int*    rowptr  = (int*)(ws + 32*MB + 96*1024);
    int*    eidsrc  = (int*)(ws + 32*MB + 128*1024);

    dim3 blk(256);
    dim3 gemmCC(4, 64);

    prep_w<<<dim3(384, 8), blk, 0, stream>>>(gin_w1, gin_w2, wq, wk, wv, wo, mw1, mw2, Wb);
    hipMemsetAsync(stats, 0, 9 * 2 * C * sizeof(float), stream);
    lin1_kernel<<<NN, blk, 0, stream>>>(x, lin1_w, lin1_b, Hb);
    hipMemsetAsync(cursor, 0, NN * sizeof(int), stream);
    hist_kernel<<<NE/256, blk, 0, stream>>>(ei, cursor);
    scan_kernel<<<1, blk, 0, stream>>>(cursor, rowptr, cursor);
    fill_kernel<<<NE/256, blk, 0, stream>>>(ei, cursor, eidsrc);

    for (int l = 0; l < NL; l++) {
        const __bf16* gw1b = Wb + (size_t)l*CC1;
        const __bf16* gw2b = Wb + (size_t)(3+l)*CC1;
        const __bf16* wqkv = Wb + (size_t)(6+3*l)*CC1;
        const __bf16* wop  = Wb + (size_t)(15+l)*CC1;
        const __bf16* mw1p = Wb + (size_t)(18+2*l)*CC1;
        const __bf16* mw2p = Wb + (size_t)(24+2*l)*CC1;
        const float* gb1 = gin_b1 + (size_t)l*C;
        const float* gb2 = gin_b2 + (size_t)l*C;
        const float* lbq = bq + (size_t)l*C;
        const float* lbk = bk + (size_t)l*C;
        const float* lbv = bv + (size_t)l*C;
        const float* lbo = bo + (size_t)l*C;
        const float* lmb1 = mb1 + (size_t)l*2*C;
        const float* lmb2 = mb2 + (size_t)l*C;
        float* st1 = stats + (size_t)l*3*2*C;
        float* st2 = st1 + 2*C;
        float* st3 = st2 + 2*C;

        // ---- fused stacked-QKV projection + gather aggregation ----
        qkv_agg_kernel<<<768 + NN/4, blk, 0, stream>>>(Hb, wqkv, lbq, lbk, lbv,
                QKbuf, Vt, rowptr, eidsrc, agg);
        // ---- GIN MLP ----
        gemm_bf16<<<gemmCC, blk, 0, stream>>>(Hb, agg, nullptr, gw1b, gb1,
                nullptr, nullptr, z1b, nullptr, C, C, 1);
        gemm_bf16<<<gemmCC, blk, 0, stream>>>(z1b, nullptr, nullptr, gw2b, gb2,
                Hb, nullptr, zbufG, st1, C, C, 0);
        bn_apply_kernel<<<NN/4, blk, 0, stream>>>(zbufG, st1, bn1_g + (size_t)l*C,
                bn1_b + (size_t)l*C, h1b, nullptr);
        // ---- attention ----
        attn_kernel<<<dim3(NN/128, NH, SPLIT), blk, 0, stream>>>(QKbuf, Vt, Opart, Oml);
        attn_combine<<<NN, blk, 0, stream>>>(Opart, Oml, Ob);
        gemm_bf16<<<gemmCC, blk, 0, stream>>>(Ob, nullptr, nullptr, wop, lbo,
                Hb, nullptr, zbuf, st2, C, C, 0);
        bn_apply_kernel<<<NN/4, blk, 0, stream>>>(zbuf, st2, bn2_g + (size_t)l*C,
                bn2_b + (size_t)l*C, h2b, nullptr);
        // ---- feedforward: s = h1 + h2 fused via A2b ----
        gemm_bf16<<<dim3(8, 64), blk, 0, stream>>>(h1b, nullptr, h2b, mw1p, lmb1,
                nullptr, nullptr, hiddenb, nullptr, C, 2*C, 1);
        gemm_bf16<<<gemmCC, blk, 0, stream>>>(hiddenb, nullptr, nullptr, mw2p, lmb2,
                h1b, h2b, zbuf, st3, 2*C, C, 0);
        if (l == NL-1)
            bn_apply_kernel<<<NN/4, blk, 0, stream>>>(zbuf, st3, bn3_g + (size_t)l*C,
                    bn3_b + (size_t)l*C, nullptr, (float*)d_out);
        else
            bn_apply_kernel<<<NN/4, blk, 0, stream>>>(zbuf, st3, bn3_g + (size_t)l*C,
                    bn3_b + (size_t)l*C, Hb, nullptr);
    }
}